// Round 5
// baseline (962.304 us; speedup 1.0000x reference)
//
#include <hip/hip_runtime.h>
#include <math.h>

#define Bn 4
#define Cn 32
#define Dn 64
#define Hn 64
#define Wn 64
#define PLANE (Hn * Wn)    // 4096
#define DT 16              // d-planes per block

// Exact-grade GELU: 0.5x(1+erf(x/sqrt2)) with A&S 7.1.26 erf (max abs err 1.5e-7).
__device__ __forceinline__ float gelu_exact(float x) {
    float s = fabsf(x) * 0.70710678118654752f;
    float t = __builtin_amdgcn_rcpf(fmaf(0.3275911f, s, 1.0f));
    float P = t * fmaf(t, fmaf(t, fmaf(t, fmaf(t, 1.061405429f, -1.453152027f),
                                       1.421413741f), -0.284496736f), 0.254829592f);
    float E = __builtin_amdgcn_exp2f(-s * s * 1.4426950408889634f);
    float q = P * E;
    float hxq = 0.5f * x * q;
    return x > 0.f ? x - hxq : hxq;
}

__device__ __forceinline__ void acc_row(const float f[10], float w0t, float w1t,
                                        float w2t, float acc[8]) {
#pragma unroll
    for (int j = 0; j < 8; j++) {
        acc[j] = fmaf(f[j],     w0t, acc[j]);
        acc[j] = fmaf(f[j + 1], w1t, acc[j]);
        acc[j] = fmaf(f[j + 2], w2t, acc[j]);
    }
}

// One step: dst = gelu(src + depthwise_conv3x3x3(src)), zero padding.
// NO-LDS DESIGN. Rounds 0-4 showed every LDS-staged variant pinned at 91-101 us
// with no pipe saturated (VALU 36%, LDS ~40%, HBM ~30%) regardless of barrier
// topology: the global->reg->shfl->ds_write->barrier->ds_read round-trip IS the
// cost. Here each thread loads its 3 rows of the fresh plane straight from
// global (aligned dwordx4; 3x read amplification served by L1/L2 — per-iter
// block read set 48 KB, per-XCD working set ~3 MB < 4 MB L2), w-halo comes from
// neighbor lanes via __shfl, and 3 SLIDING ACCUMULATORS (A0/A1/A2, rotated by
// compile-time name permutation — persistent arrays only, constant indices, no
// lambdas/by-ref: avoids the R1/R3 scratch-demotion modes) integrate plane p
// into outputs p-1/p/p+1 with the kz=2/1/0 weight slabs. Output p-1 finishes and
// stores immediately. Zero barriers, zero LDS.
__global__ __launch_bounds__(512, 4)
void EmergentSpatialPropagation_step(const float* __restrict__ src,
                                     const float* __restrict__ wgt,
                                     float* __restrict__ dst) {
    const int tid = threadIdx.x;
    const int d0  = blockIdx.x * DT;
    const int c   = blockIdx.y;
    const int b   = blockIdx.z;
    const size_t base = ((size_t)(b * Cn + c)) * (size_t)(Dn * PLANE);

    float wt[27];
#pragma unroll
    for (int k = 0; k < 27; k++) wt[k] = wgt[c * 27 + k];   // block-uniform -> SGPR

    const int h  = tid >> 3;          // output row 0..63
    const int w0 = (tid & 7) << 3;    // output col group
    const int lw = tid & 7;           // lane-in-row-group (w-halo shfl roles)

    // h-clamped neighbor rows (always-valid addresses; results zeroed at edges).
    const int hm = (h == 0) ? 0 : h - 1;
    const int hp = (h == Hn - 1) ? Hn - 1 : h + 1;
    const bool has_m = (h > 0);
    const bool has_p = (h < Hn - 1);

    const int offm = hm * Wn + w0;
    const int offc = h  * Wn + w0;
    const int offp = hp * Wn + w0;

    const float4 z4 = make_float4(0.f, 0.f, 0.f, 0.f);

    // Sliding accumulators (persistent; rotated by name, never by index).
    float A0[8], A1[8], A2[8];
#pragma unroll
    for (int j = 0; j < 8; j++) { A0[j] = 0.f; A1[j] = 0.f; A2[j] = 0.f; }

    // Center-row values of the previous plane (the gelu residual input).
    float4 pcx0 = z4, pcx1 = z4;

// Build the 10-float sliding window of a row: cols w0-1 .. w0+8.
// Left/right edge values come from neighbor lanes' registers via shfl
// (lane k-1 holds col w0-1 as its L1.w; lane k+1 holds col w0+8 as its L0.x).
#define ROW_WIN(F, R0v, R1v)                          \
    {                                                 \
        float el = __shfl_up((R1v).w, 1);             \
        float er = __shfl_down((R0v).x, 1);           \
        F[0] = (lw == 0) ? 0.f : el;                  \
        F[1] = (R0v).x; F[2] = (R0v).y;               \
        F[3] = (R0v).z; F[4] = (R0v).w;               \
        F[5] = (R1v).x; F[6] = (R1v).y;               \
        F[7] = (R1v).z; F[8] = (R1v).w;               \
        F[9] = (lw == 7) ? 0.f : er;                  \
    }

// One sliding-window iteration: load plane p = d0-1+JJ, accumulate its
// contribution into AH (output p+1, kz=0 slab), AM (output p, kz=1),
// AL (output p-1, kz=2), then finalize+store AL (output p-1) and clear it
// (the cleared AL is next iteration's AH). DOL/DOM/DOH are compile-time
// flags that trim the out-of-range prologue/epilogue slabs.
#define BODY(JJ, AL, AM, AH, DOL, DOM, DOH)                                    \
    do {                                                                       \
        const int p = d0 - 1 + (JJ);                                           \
        float4 m0, m1, c0, c1, q0, q1;                                         \
        if ((unsigned)p < (unsigned)Dn) {                                      \
            const float* g = src + base + (size_t)p * PLANE;                   \
            m0 = *(const float4*)(g + offm); m1 = *(const float4*)(g + offm + 4); \
            c0 = *(const float4*)(g + offc); c1 = *(const float4*)(g + offc + 4); \
            q0 = *(const float4*)(g + offp); q1 = *(const float4*)(g + offp + 4); \
            if (!has_m) { m0 = z4; m1 = z4; }                                  \
            if (!has_p) { q0 = z4; q1 = z4; }                                  \
        } else {                                                               \
            m0 = z4; m1 = z4; c0 = z4; c1 = z4; q0 = z4; q1 = z4;              \
        }                                                                      \
        float fm[10], fc[10], fq[10];                                          \
        ROW_WIN(fm, m0, m1); ROW_WIN(fc, c0, c1); ROW_WIN(fq, q0, q1);         \
        if (DOH) {                      /* output p+1: plane p is its dz-1 */  \
            acc_row(fm, wt[0], wt[1], wt[2], AH);                              \
            acc_row(fc, wt[3], wt[4], wt[5], AH);                              \
            acc_row(fq, wt[6], wt[7], wt[8], AH);                              \
        }                                                                      \
        if (DOM) {                      /* output p: plane p is its center */  \
            acc_row(fm, wt[9],  wt[10], wt[11], AM);                           \
            acc_row(fc, wt[12], wt[13], wt[14], AM);                           \
            acc_row(fq, wt[15], wt[16], wt[17], AM);                           \
        }                                                                      \
        if (DOL) {                      /* output p-1: plane p is its dz+1 */  \
            acc_row(fm, wt[18], wt[19], wt[20], AL);                           \
            acc_row(fc, wt[21], wt[22], wt[23], AL);                           \
            acc_row(fq, wt[24], wt[25], wt[26], AL);                           \
            float* dp = dst + base + (size_t)(p - 1) * PLANE + offc;           \
            float4 o0 = make_float4(gelu_exact(pcx0.x + AL[0]),                \
                                    gelu_exact(pcx0.y + AL[1]),                \
                                    gelu_exact(pcx0.z + AL[2]),                \
                                    gelu_exact(pcx0.w + AL[3]));               \
            float4 o1 = make_float4(gelu_exact(pcx1.x + AL[4]),                \
                                    gelu_exact(pcx1.y + AL[5]),                \
                                    gelu_exact(pcx1.z + AL[6]),                \
                                    gelu_exact(pcx1.w + AL[7]));               \
            *(float4*)(dp)     = o0;    /* w0 multiple of 8 -> 32B-aligned */  \
            *(float4*)(dp + 4) = o1;                                           \
        }                                                                      \
        _Pragma("unroll")                                                      \
        for (int j = 0; j < 8; j++) AL[j] = 0.f;   /* becomes next AH */       \
        pcx0 = c0; pcx1 = c1;                                                  \
    } while (0)

    // 18 iterations: planes d0-1 .. d0+16; outputs d0 .. d0+15.
    // Head peel (jj=0..2): out-of-range slabs trimmed at compile time.
    BODY(0, A0, A1, A2, 0, 0, 1);
    BODY(1, A1, A2, A0, 0, 1, 1);
    BODY(2, A2, A0, A1, 1, 1, 1);
    // Steady state (jj=3..14), guard-free bodies.
#pragma unroll 1
    for (int u = 3; u < 15; u += 3) {
        BODY(u,     A0, A1, A2, 1, 1, 1);
        BODY(u + 1, A1, A2, A0, 1, 1, 1);
        BODY(u + 2, A2, A0, A1, 1, 1, 1);
    }
    // Tail peel (jj=15..17).
    BODY(15, A0, A1, A2, 1, 1, 1);
    BODY(16, A1, A2, A0, 1, 1, 0);
    BODY(17, A2, A0, A1, 1, 0, 0);

#undef BODY
#undef ROW_WIN
}

extern "C" void kernel_launch(void* const* d_in, const int* in_sizes, int n_in,
                              void* d_out, int out_size, void* d_ws, size_t ws_size,
                              hipStream_t stream) {
    const float* x   = (const float*)d_in[0];
    const float* wgt = (const float*)d_in[1];
    float* out = (float*)d_out;
    float* ws  = (float*)d_ws;

    dim3 grid(Dn / DT, Cn, Bn);   // 4 x 32 x 4 = 512 blocks -> 2/CU resident
    dim3 block(512);

    // 8 steps, ping-pong: in -> ws -> out -> ... -> out
    const float* src = x;
    for (int s = 0; s < 8; s++) {
        float* dst = (s & 1) ? out : ws;
        EmergentSpatialPropagation_step<<<grid, block, 0, stream>>>(src, wgt, dst);
        src = dst;
    }
}

// Round 8
// 644.566 us; speedup vs baseline: 1.4929x; 1.4929x over previous
//
#include <hip/hip_runtime.h>
#include <math.h>

#define Bn 4
#define Cn 32
#define Dn 64
#define Hn 64
#define Wn 64
#define PLANE (Hn * Wn)    // 4096
#define DT 8               // d-planes per block
#define HT 32              // h-rows per block (H split in 2)
#define LSTRIDE 68         // padded row stride: 68*4 = 272 B = 17*16 (rows 16B-aligned)
#define LROWS (HT + 2)     // 34: padded rows 0..33 hold data rows h0-1..h0+32
#define LPLANE (LROWS * LSTRIDE)   // 2312 floats = 9248 B

// Exact-grade GELU: 0.5x(1+erf(x/sqrt2)) with A&S 7.1.26 erf (max abs err 1.5e-7).
__device__ __forceinline__ float gelu_exact(float x) {
    float s = fabsf(x) * 0.70710678118654752f;
    float t = __builtin_amdgcn_rcpf(fmaf(0.3275911f, s, 1.0f));
    float P = t * fmaf(t, fmaf(t, fmaf(t, fmaf(t, 1.061405429f, -1.453152027f),
                                       1.421413741f), -0.284496736f), 0.254829592f);
    float E = __builtin_amdgcn_exp2f(-s * s * 1.4426950408889634f);
    float q = P * E;
    float hxq = 0.5f * x * q;
    return x > 0.f ? x - hxq : hxq;
}

__device__ __forceinline__ void read_row(const float* base, float f[10]) {
    float4 a = *(const float4*)(base);       // 16B-aligned (LSTRIDE*4 = 17*16)
    float4 b = *(const float4*)(base + 4);
    float2 c = *(const float2*)(base + 8);
    f[0] = a.x; f[1] = a.y; f[2] = a.z; f[3] = a.w;
    f[4] = b.x; f[5] = b.y; f[6] = b.z; f[7] = b.w;
    f[8] = c.x; f[9] = c.y;
}

__device__ __forceinline__ void acc_row(const float f[10], float w0t, float w1t,
                                        float w2t, float acc[8]) {
#pragma unroll
    for (int j = 0; j < 8; j++) {
        acc[j] = fmaf(f[j],     w0t, acc[j]);
        acc[j] = fmaf(f[j + 1], w1t, acc[j]);
        acc[j] = fmaf(f[j + 2], w2t, acc[j]);
    }
}

// One step: dst = gelu(src + depthwise_conv3x3x3(src)), zero padding.
// Hypothesis (R5): latency-bound at 16 waves/CU. Fix: 32 waves/CU.
//  - SLIDING ACCUMULATORS over d: each plane is ds_read ONCE (3 rows) and
//    FMA'd into 3 output accumulators (outputs p+1/p/p-1 via kz=0/1/2 slabs).
//    Output p-1 completes and stores. Live LDS window = 2 planes.
//  - 2-SLOT PING-PONG, 18.5 KB/block; DT=8 x HT=32, 256 threads, grid 2048
//    -> 8 blocks/CU = 32 waves/CU (2x every prior round).
//  - Register discipline: persistent FIXED-name arrays, explicit copy-rotation
//    (the only non-spilling pattern across R0-R5).
//  - vs the twice-failed R6 source (no GPU verdict either time): the peeled
//    12-instantiation macro is replaced by ONE uniform loop — all 27 taps every
//    iter; head/tail accumulators holding out-of-range outputs are provably
//    discarded by the rotation before the store guard (jj>=2) opens. ~6x less
//    emitted code, no constant-flag branches, same numerics (stored outputs'
//    FMA sequences are identical).
__global__ __launch_bounds__(256, 4)
void EmergentSpatialPropagation_step(const float* __restrict__ src,
                                     const float* __restrict__ wgt,
                                     float* __restrict__ dst) {
    __shared__ __align__(16) float lds[2 * LPLANE];   // 18496 B -> 8 blocks/CU

    const int tid  = threadIdx.x;
    const int dblk = blockIdx.x >> 1;
    const int hblk = blockIdx.x & 1;
    const int d0   = dblk * DT;
    const int h0   = hblk * HT;
    const int c    = blockIdx.y;
    const int b    = blockIdx.z;
    const size_t base = ((size_t)(b * Cn + c)) * (size_t)(Dn * PLANE);

    // Zero both slots once; never-rewritten pad cells stay zero.
    for (int i = tid; i < 2 * LPLANE; i += 256) lds[i] = 0.0f;

    float wt[27];
#pragma unroll
    for (int k = 0; k < 27; k++) wt[k] = wgt[c * 27 + k];   // block-uniform -> SGPR

    const int h  = tid >> 3;          // local output row 0..31
    const int w0 = (tid & 7) << 3;    // output col group
    const int m  = tid & 15;          // staging lane role (16 lanes per row)

    // Plane p -> slot parity: plane d0-1 -> 0, d0 -> 1, ...
    auto sl = [&](int p) -> float* { return &lds[((p - d0 + 1) & 1) * LPLANE]; };

    // Global plane p -> 2 float4 main regs + 1 float4 halo reg (threads 0..31).
    auto load_g = [&](int p, float4 G[2], float4& GH) {
        GH = make_float4(0.f, 0.f, 0.f, 0.f);
        if ((unsigned)p < (unsigned)Dn) {
            const float4* g = (const float4*)(src + base + (size_t)p * PLANE);
            G[0] = g[h0 * 16 + tid];          // rows h0..h0+15
            G[1] = g[h0 * 16 + 256 + tid];    // rows h0+16..h0+31
            if (tid < 32) {
                int row = (tid < 16) ? (h0 - 1) : (h0 + HT);
                if ((unsigned)row < (unsigned)Hn) GH = g[row * 16 + (tid & 15)];
            }
        } else {
            G[0] = make_float4(0.f, 0.f, 0.f, 0.f);
            G[1] = make_float4(0.f, 0.f, 0.f, 0.f);
        }
    };

    // Regs -> LDS slot, 16B-aligned writes via shfl repack.
    // Padded group cols 4m..4m+3 hold data cols 4m-1..4m+2 = {prev.w, x, y, z}.
    auto write_plane = [&](float* pl, const float4 G[2], float4 GH) {
#pragma unroll
        for (int i = 0; i < 2; i++) {
            int idx = i * 256 + tid;
            int row = (idx >> 4) + 1;                 // padded row 1..32
            float prev = __shfl_up(G[i].w, 1);
            if (m == 0) prev = 0.f;                   // left zero halo
            float4 Wv = make_float4(prev, G[i].x, G[i].y, G[i].z);
            *(float4*)(pl + row * LSTRIDE + 4 * m) = Wv;
            if (m == 15) pl[row * LSTRIDE + 64] = G[i].w;   // data col 63
        }
        if (tid < 32) {                               // halo rows: padded 0 / 33
            int prow = (tid < 16) ? 0 : (LROWS - 1);
            float prev = __shfl_up(GH.w, 1);
            if (m == 0) prev = 0.f;
            float4 Wv = make_float4(prev, GH.x, GH.y, GH.z);
            *(float4*)(pl + prow * LSTRIDE + 4 * m) = Wv;
            if (m == 15) pl[prow * LSTRIDE + 64] = GH.w;
        }
    };

    // ---- Prologue: stage plane d0-1 (slot parity 0) ----
    __syncthreads();   // zeros visible
    {
        float4 Ga[2], Ha;
        load_g(d0 - 1, Ga, Ha);
        write_plane(sl(d0 - 1), Ga, Ha);
    }
    __syncthreads();

    // A2/A1/A0 hold outputs p+1/p/p-1 while plane p is processed.
    // prevc = center row of plane p-1 (residual input of output p-1).
    float A0[8], A1[8], A2[8], prevc[8];
#pragma unroll
    for (int j = 0; j < 8; j++) { A0[j] = 0.f; A1[j] = 0.f; A2[j] = 0.f; prevc[j] = 0.f; }

    // Planes d0-1 .. d0+DT (DT+2 iters); outputs d0 .. d0+DT-1.
#pragma unroll 1
    for (int jj = 0; jj <= DT + 1; jj++) {
        const int p = d0 - 1 + jj;
        const bool do_stage = (jj <= DT);     // block-uniform

        // Prefetch plane p+1 into regs (hidden behind the FMA block).
        float4 G[2], GH;
        if (do_stage) load_g(p + 1, G, GH);

        // Read plane p once: rows h-1, h, h+1 (padded rows h..h+2).
        float fm[10], fc[10], fq[10];
        const float* pl = sl(p);
        read_row(pl + (h + 0) * LSTRIDE + w0, fm);
        read_row(pl + (h + 1) * LSTRIDE + w0, fc);
        read_row(pl + (h + 2) * LSTRIDE + w0, fq);

        // Full 27-tap scatter of plane p into the three sliding accumulators.
        acc_row(fm, wt[0],  wt[1],  wt[2],  A2);   // -> output p+1 (kz=0)
        acc_row(fc, wt[3],  wt[4],  wt[5],  A2);
        acc_row(fq, wt[6],  wt[7],  wt[8],  A2);
        acc_row(fm, wt[9],  wt[10], wt[11], A1);   // -> output p   (kz=1)
        acc_row(fc, wt[12], wt[13], wt[14], A1);
        acc_row(fq, wt[15], wt[16], wt[17], A1);
        acc_row(fm, wt[18], wt[19], wt[20], A0);   // -> output p-1 (kz=2, final)
        acc_row(fc, wt[21], wt[22], wt[23], A0);
        acc_row(fq, wt[24], wt[25], wt[26], A0);

        // Store output p-1 (complete). jj<2 holders are out-of-range outputs
        // d0-2/d0-1: never stored, rotated away below.
        if (jj >= 2) {
            float* dp = dst + base + (size_t)(p - 1) * PLANE + (h0 + h) * Wn + w0;
            float4 o0 = make_float4(gelu_exact(prevc[0] + A0[0]),
                                    gelu_exact(prevc[1] + A0[1]),
                                    gelu_exact(prevc[2] + A0[2]),
                                    gelu_exact(prevc[3] + A0[3]));
            float4 o1 = make_float4(gelu_exact(prevc[4] + A0[4]),
                                    gelu_exact(prevc[5] + A0[5]),
                                    gelu_exact(prevc[6] + A0[6]),
                                    gelu_exact(prevc[7] + A0[7]));
            *(float4*)(dp)     = o0;    // w0 multiple of 8 -> 32B-aligned
            *(float4*)(dp + 4) = o1;
        }

        // Slide: freed A0 becomes the new (zeroed) A2.
#pragma unroll
        for (int j = 0; j < 8; j++) { A0[j] = A1[j]; A1[j] = A2[j]; A2[j] = 0.f; }
#pragma unroll
        for (int j = 0; j < 8; j++) prevc[j] = fc[j + 1];

        if (do_stage) {
            write_plane(sl(p + 1), G, GH);   // other slot: read last iter
            __syncthreads();                 // single barrier per iteration
        }
    }
}

extern "C" void kernel_launch(void* const* d_in, const int* in_sizes, int n_in,
                              void* d_out, int out_size, void* d_ws, size_t ws_size,
                              hipStream_t stream) {
    const float* x   = (const float*)d_in[0];
    const float* wgt = (const float*)d_in[1];
    float* out = (float*)d_out;
    float* ws  = (float*)d_ws;

    dim3 grid((Dn / DT) * 2, Cn, Bn);   // (8 d-blks x 2 h-blks) x 32 x 4 = 2048 -> 8/CU
    dim3 block(256);

    // 8 steps, ping-pong: in -> ws -> out -> ... -> out
    const float* src = x;
    for (int s = 0; s < 8; s++) {
        float* dst = (s & 1) ? out : ws;
        EmergentSpatialPropagation_step<<<grid, block, 0, stream>>>(src, wgt, dst);
        src = dst;
    }
}